// Round 3
// baseline (691.483 us; speedup 1.0000x reference)
//
#include <hip/hip_runtime.h>
#include <math.h>

// Problem constants (from reference)
#define B_ 64
#define C_ 512
#define HW_ 3136            // 56*56
#define HW4_ 784            // 3136/4 float4 per plane
#define K9_ 9
#define SK_ (C_ * K9_)      // 4608 = per-out-channel weight length
#define NPLANES_ (B_ * C_)  // 32768
#define NOUT_ ((size_t)B_ * C_ * HW_)   // 102,760,448 elements of `out`

// Kernel 1: s[c*9+k] = sum_b ssty[b, c, k]   (4608 outputs, 64-way sum)
__global__ void batch_reduce_kernel(const float* __restrict__ ssty,
                                    float* __restrict__ s) {
    int idx = blockIdx.x * blockDim.x + threadIdx.x;
    if (idx >= SK_) return;
    float acc = 0.f;
    #pragma unroll 8
    for (int b = 0; b < B_; ++b) {
        acc += ssty[(size_t)b * SK_ + idx];
    }
    s[idx] = acc;
}

// Kernel 2: mask[o] = sigmoid((dot(s, w[o]) + bias[o]) * beta)
// One 256-thread block per output channel o. NOT fused with kernel 1:
// fusing would make each of the 512 blocks re-read all of ssty (604 MB
// redundant traffic) vs two tiny launches.
__global__ void mask_kernel(const float* __restrict__ s,
                            const float* __restrict__ w,
                            const float* __restrict__ bias,
                            const float* __restrict__ beta,
                            float* __restrict__ mask_ws,
                            float* __restrict__ mask_out) {
    int o = blockIdx.x;
    const float* wo = w + (size_t)o * SK_;
    float p = 0.f;
    // 4608 = 18 * 256 → exactly 18 iterations per thread, coalesced
    for (int i = threadIdx.x; i < SK_; i += 256) {
        p += s[i] * wo[i];
    }
    // wave64 butterfly reduce
    #pragma unroll
    for (int off = 32; off > 0; off >>= 1) {
        p += __shfl_down(p, off, 64);
    }
    __shared__ float red[4];
    int wid = threadIdx.x >> 6;
    if ((threadIdx.x & 63) == 0) red[wid] = p;
    __syncthreads();
    if (threadIdx.x == 0) {
        float m = red[0] + red[1] + red[2] + red[3] + bias[o];
        float v = 1.f / (1.f + expf(-m * beta[0]));
        mask_ws[o] = v;
        mask_out[o] = v;   // second tuple element in d_out tail
    }
}

// Kernel 3: out[b,c,:,:] = x[b,c,:,:] * mask[c], float4-vectorized.
// Grid-stride over planes: 2048 blocks x 256 threads, 16 planes/block
// (~8 blocks/CU — Guideline 11 streaming config).
__global__ void __launch_bounds__(256) scale_kernel(const float4* __restrict__ x,
                                                    const float* __restrict__ mask,
                                                    float4* __restrict__ out) {
    for (int plane = blockIdx.x; plane < NPLANES_; plane += gridDim.x) {
        int c = plane & (C_ - 1);        // C=512 is a power of two
        float mv = mask[c];              // block-step-uniform, L1/L2-cached
        const float4* xp = x + (size_t)plane * HW4_;
        float4* op = out + (size_t)plane * HW4_;
        // 784 = 3*256 + 16 → threads 0..15 do 4 iters, rest 3
        for (int i = threadIdx.x; i < HW4_; i += 256) {
            float4 v = xp[i];
            v.x *= mv; v.y *= mv; v.z *= mv; v.w *= mv;
            op[i] = v;
        }
    }
}

extern "C" void kernel_launch(void* const* d_in, const int* in_sizes, int n_in,
                              void* d_out, int out_size, void* d_ws, size_t ws_size,
                              hipStream_t stream) {
    const float* x      = (const float*)d_in[0];  // [64,512,56,56]
    const float* ssty   = (const float*)d_in[1];  // [64,512,3,3]
    const float* beta   = (const float*)d_in[2];  // [1]
    const float* conv_w = (const float*)d_in[3];  // [512,512,3,3]
    const float* conv_b = (const float*)d_in[4];  // [512]

    float* out      = (float*)d_out;              // [64,512,56,56] then mask[512]
    float* mask_out = out + NOUT_;

    float* s_ws    = (float*)d_ws;                // 4608 floats
    float* mask_ws = s_ws + SK_;                  // 512 floats

    // 1) batch-reduce ssty -> s
    batch_reduce_kernel<<<(SK_ + 255) / 256, 256, 0, stream>>>(ssty, s_ws);

    // 2) per-channel dot + sigmoid -> mask (ws + d_out tail)
    mask_kernel<<<C_, 256, 0, stream>>>(s_ws, conv_w, conv_b, beta,
                                        mask_ws, mask_out);

    // 3) broadcast multiply (the memory-bound bulk)
    scale_kernel<<<2048, 256, 0, stream>>>((const float4*)x, mask_ws,
                                           (float4*)out);
}

// Round 9
// 671.651 us; speedup vs baseline: 1.0295x; 1.0295x over previous
//
#include <hip/hip_runtime.h>
#include <math.h>

// Problem constants (from reference)
#define B_ 64
#define C_ 512
#define HW_ 3136            // 56*56
#define HW4_ 784            // 3136/4 float4 per plane
#define K9_ 9
#define SK_ (C_ * K9_)      // 4608 = per-out-channel weight length
#define NPLANES_ (B_ * C_)  // 32768
#define NOUT_ ((size_t)B_ * C_ * HW_)   // 102,760,448 elements of `out`

// clang ext_vector_type: accepted by __builtin_nontemporal_*, same layout
// as float4 (16 B, 4 x f32).
typedef float f32x4 __attribute__((ext_vector_type(4)));

// Kernel 1: s[c*9+k] = sum_b ssty[b, c, k]   (4608 outputs, 64-way sum)
__global__ void batch_reduce_kernel(const float* __restrict__ ssty,
                                    float* __restrict__ s) {
    int idx = blockIdx.x * blockDim.x + threadIdx.x;
    if (idx >= SK_) return;
    float acc = 0.f;
    #pragma unroll 8
    for (int b = 0; b < B_; ++b) {
        acc += ssty[(size_t)b * SK_ + idx];
    }
    s[idx] = acc;
}

// Kernel 2: mask[o] = sigmoid((dot(s, w[o]) + bias[o]) * beta)
// One 256-thread block per output channel o; float4 weight loads.
// NOT fused with kernel 1: fusing would make each of the 512 blocks
// re-read all of ssty (604 MB redundant traffic).
__global__ void mask_kernel(const float* __restrict__ s,
                            const float* __restrict__ w,
                            const float* __restrict__ bias,
                            const float* __restrict__ beta,
                            float* __restrict__ mask_ws,
                            float* __restrict__ mask_out) {
    int o = blockIdx.x;
    const f32x4* wo = (const f32x4*)(w + (size_t)o * SK_);
    const f32x4* s4 = (const f32x4*)s;
    float p = 0.f;
    // 4608/4 = 1152 float4 → 4.5 iters per thread at 256 threads
    for (int i = threadIdx.x; i < SK_ / 4; i += 256) {
        f32x4 a = s4[i];
        f32x4 b = wo[i];
        p += a.x * b.x + a.y * b.y + a.z * b.z + a.w * b.w;
    }
    // wave64 butterfly reduce
    #pragma unroll
    for (int off = 32; off > 0; off >>= 1) {
        p += __shfl_down(p, off, 64);
    }
    __shared__ float red[4];
    int wid = threadIdx.x >> 6;
    if ((threadIdx.x & 63) == 0) red[wid] = p;
    __syncthreads();
    if (threadIdx.x == 0) {
        float m = red[0] + red[1] + red[2] + red[3] + bias[o];
        float v = 1.f / (1.f + expf(-m * beta[0]));
        mask_ws[o] = v;
        mask_out[o] = v;   // second tuple element in d_out tail
    }
}

// Kernel 3: out[b,c,:,:] = x[b,c,:,:] * mask[c], f32x4 + non-temporal.
// Grid-stride over planes: 2048 blocks x 256 threads (8 blocks/CU, 32
// waves/CU = max occupancy). Pure streaming, no reuse -> nt hints.
__global__ void __launch_bounds__(256) scale_kernel(const f32x4* __restrict__ x,
                                                    const float* __restrict__ mask,
                                                    f32x4* __restrict__ out) {
    for (int plane = blockIdx.x; plane < NPLANES_; plane += gridDim.x) {
        int c = plane & (C_ - 1);        // C=512 is a power of two
        float mv = mask[c];              // block-step-uniform, L1-cached
        const f32x4* xp = x + (size_t)plane * HW4_;
        f32x4* op = out + (size_t)plane * HW4_;
        // 784 = 3*256 + 16 → threads 0..15 do 4 iters, rest 3
        for (int i = threadIdx.x; i < HW4_; i += 256) {
            f32x4 v = __builtin_nontemporal_load(&xp[i]);
            v *= mv;
            __builtin_nontemporal_store(v, &op[i]);
        }
    }
}

extern "C" void kernel_launch(void* const* d_in, const int* in_sizes, int n_in,
                              void* d_out, int out_size, void* d_ws, size_t ws_size,
                              hipStream_t stream) {
    const float* x      = (const float*)d_in[0];  // [64,512,56,56]
    const float* ssty   = (const float*)d_in[1];  // [64,512,3,3]
    const float* beta   = (const float*)d_in[2];  // [1]
    const float* conv_w = (const float*)d_in[3];  // [512,512,3,3]
    const float* conv_b = (const float*)d_in[4];  // [512]

    float* out      = (float*)d_out;              // [64,512,56,56] then mask[512]
    float* mask_out = out + NOUT_;

    float* s_ws    = (float*)d_ws;                // 4608 floats
    float* mask_ws = s_ws + SK_;                  // 512 floats

    // 1) batch-reduce ssty -> s
    batch_reduce_kernel<<<(SK_ + 255) / 256, 256, 0, stream>>>(ssty, s_ws);

    // 2) per-channel dot + sigmoid -> mask (ws + d_out tail)
    mask_kernel<<<C_, 256, 0, stream>>>(s_ws, conv_w, conv_b, beta,
                                        mask_ws, mask_out);

    // 3) broadcast multiply (the memory-bound bulk)
    scale_kernel<<<2048, 256, 0, stream>>>((const f32x4*)x, mask_ws,
                                           (f32x4*)out);
}